// Round 1
// baseline (3526.714 us; speedup 1.0000x reference)
//
#include <hip/hip_runtime.h>
#include <cstdint>
#include <cstddef>

typedef unsigned int  u32;
typedef unsigned short u16;
typedef _Float16 f16;
typedef _Float16 f16x2 __attribute__((ext_vector_type(2)));

#define BATCH 64
#define TSEQ  512
#define DEMB  300
#define HDIM  256
#define G4    1024
#define NCLS  9

__device__ __forceinline__ float fdot2(u32 a, u32 b, float c) {
#if __has_builtin(__builtin_amdgcn_fdot2)
  return __builtin_amdgcn_fdot2(__builtin_bit_cast(f16x2, a),
                                __builtin_bit_cast(f16x2, b), c, false);
#else
  f16x2 av = __builtin_bit_cast(f16x2, a), bv = __builtin_bit_cast(f16x2, b);
  return c + (float)av.x * (float)bv.x + (float)av.y * (float)bv.y;
#endif
}

__device__ __forceinline__ u32 packf16(float a, float b) {
  f16x2 v; v.x = (f16)a; v.y = (f16)b;
  return __builtin_bit_cast(u32, v);
}

// ---------------- K0: zero the sync flags ----------------
__global__ void init_k(int* __restrict__ flags) {
  flags[threadIdx.x] = 0;
}

// ---------------- K1: xz = emb[inputs] @ Wk + b  (f16 dot2 GEMM) ----------------
// M = B*T = 32768, K = 300, N = 2048 (cols 0..1023 fwd, 1024..2047 bwd)
__global__ __launch_bounds__(256) void xz_gemm_k(
    const int* __restrict__ inputs, const float* __restrict__ emb,
    const float* __restrict__ Wk_f, const float* __restrict__ b_f,
    const float* __restrict__ Wk_b, const float* __restrict__ b_b,
    u16* __restrict__ xz)
{
  __shared__ f16 As[10][128][2];   // [k-pair][row][parity]
  __shared__ f16 Bs[10][128][2];   // [k-pair][col][parity]
  const int tid = threadIdx.x;
  const int cb  = blockIdx.x * 128;      // 0..1920
  const int rb  = blockIdx.y * 128;
  const int dir = cb >> 10;
  const int cb1 = cb & 1023;
  const float* __restrict__ Wk   = dir ? Wk_b : Wk_f;
  const float* __restrict__ bias = dir ? b_b : b_f;
  const int tx = tid & 15, ty = tid >> 4;
  float acc[8][8];
#pragma unroll
  for (int i = 0; i < 8; ++i)
#pragma unroll
    for (int s = 0; s < 8; ++s) acc[i][s] = 0.f;

  for (int kt = 0; kt < 15; ++kt) {      // 15 * 20 = 300
    const int k0 = kt * 20;
#pragma unroll
    for (int i = 0; i < 10; ++i) {       // stage A: 128 rows x 20 k
      int e = tid * 10 + i;
      int r = e / 20, kk = e - r * 20;
      int v = inputs[rb + r];
      As[kk >> 1][r][kk & 1] = (f16)emb[(size_t)v * DEMB + k0 + kk];
    }
#pragma unroll
    for (int i = 0; i < 10; ++i) {       // stage B: 20 k x 128 cols
      int e = i * 256 + tid;
      int kk = e >> 7, c = e & 127;
      Bs[kk >> 1][c][kk & 1] = (f16)Wk[(size_t)(k0 + kk) * G4 + cb1 + c];
    }
    __syncthreads();
#pragma unroll
    for (int j = 0; j < 10; ++j) {
      u32 a2[8], b2[8];
#pragma unroll
      for (int i = 0; i < 8; ++i) a2[i] = *(const u32*)&As[j][ty * 8 + i][0];
#pragma unroll
      for (int s = 0; s < 8; ++s) b2[s] = *(const u32*)&Bs[j][s * 16 + tx][0];
#pragma unroll
      for (int i = 0; i < 8; ++i)
#pragma unroll
        for (int s = 0; s < 8; ++s)
          acc[i][s] = fdot2(a2[i], b2[s], acc[i][s]);
    }
    __syncthreads();
  }
#pragma unroll
  for (int i = 0; i < 8; ++i) {
    const int row = rb + ty * 8 + i;     // row = batch*512 + t
#pragma unroll
    for (int s = 0; s < 8; ++s) {
      const int col = cb1 + s * 16 + tx;
      float v = acc[i][s] + bias[col];
      f16 hv = (f16)v;
      xz[((size_t)dir * BATCH * TSEQ + row) * G4 + col] = __builtin_bit_cast(u16, hv);
    }
  }
}

// ---------------- K2: LSTM recurrence ----------------
// 256 blocks: blockIdx = chain + 128*side.  chain = dir*64 + batch.
// Each block owns 512 gate columns {g*256 + side*128 + kk}, f16 weights in VGPRs.
__global__ __launch_bounds__(512) void lstm_k(
    const u16* __restrict__ xz, const float* __restrict__ Wr_f,
    const float* __restrict__ Wr_b, const int* __restrict__ lengths,
    float* __restrict__ hcat, int* __restrict__ flags, u32* __restrict__ xchg)
{
  const int side  = blockIdx.x >> 7;     // which half of H
  const int chain = blockIdx.x & 127;
  const int dir   = chain >> 6;
  const int batch = chain & 63;
  const int tid = threadIdx.x;
  const int g  = tid >> 7, kk = tid & 127;
  const int kg  = side * 128 + kk;       // h index this column feeds
  const int col = g * 256 + kg;          // gate column in [0,1024)
  const float* __restrict__ Wr = dir ? Wr_b : Wr_f;

  u32 wreg[128];                         // f16x2 packed column of Wr
#pragma unroll
  for (int j = 0; j < 128; ++j) {
    float w0 = Wr[(size_t)(2 * j) * G4 + col];
    float w1 = Wr[(size_t)(2 * j + 1) * G4 + col];
    wreg[j] = packf16(w0, w1);
  }

  __shared__ __align__(16) u32 hp[128];  // packed h pairs, full 256
  __shared__ float zbuf[512];
  if (tid < 128) hp[tid] = 0u;
  float c = 0.f, h = 0.f;
  const int len = lengths[batch];
  const u16* __restrict__ xzb = xz + (size_t)(dir * BATCH + batch) * TSEQ * G4 + col;
  float* __restrict__ hrow = hcat + (size_t)batch * TSEQ * 512 + dir * 256;
  const int myflag = chain * 2 + side;
  const int pflag  = chain * 2 + (1 - side);
  u32* __restrict__ xmy = xchg + (size_t)myflag * 2 * 64;
  u32* __restrict__ xpr = xchg + (size_t)pflag * 2 * 64;
  __syncthreads();

  int tt = dir ? (TSEQ - 1) : 0;
  const int ttstep = dir ? -1 : 1;
  u16 xzu = xzb[(size_t)tt * G4];

  for (int st = 0; st < TSEQ; ++st) {
    int ttn = (st == TSEQ - 1) ? tt : tt + ttstep;
    u16 xzun = xzb[(size_t)ttn * G4];    // prefetch next step's xz

    float acc = 0.f;
#pragma unroll
    for (int jj = 0; jj < 8; ++jj) {
#pragma unroll
      for (int q = 0; q < 4; ++q) {
        uint4 hv4 = *(const uint4*)&hp[jj * 16 + q * 4];
        acc = fdot2(wreg[jj * 16 + q * 4 + 0], hv4.x, acc);
        acc = fdot2(wreg[jj * 16 + q * 4 + 1], hv4.y, acc);
        acc = fdot2(wreg[jj * 16 + q * 4 + 2], hv4.z, acc);
        acc = fdot2(wreg[jj * 16 + q * 4 + 3], hv4.w, acc);
      }
    }
    f16 xzh = __builtin_bit_cast(f16, xzu);
    acc += (float)xzh;
    zbuf[tid] = acc;                     // layout [g*128 + kk] == tid
    __syncthreads();

    if (tid < 128) {                     // waves 0,1: combine gates for k = kg
      float zi = zbuf[tid], zf = zbuf[128 + tid];
      float zg = zbuf[256 + tid], zo = zbuf[384 + tid];
      float ig = 1.f / (1.f + __expf(-zi));
      float fg = 1.f / (1.f + __expf(-zf));
      float gg = tanhf(zg);
      float og = 1.f / (1.f + __expf(-zo));
      float cn = fg * c + ig * gg;
      float hn = og * tanhf(cn);
      if (tt < len) { c = cn; h = hn; }  // masked step: hold state
      hrow[(size_t)tt * 512 + kg] = h;   // fp32 h for dense layer
      float ho = __shfl_xor(h, 1);
      if ((tid & 1) == 0) {
        u32 p = packf16(h, ho);
        hp[side * 64 + (tid >> 1)] = p;  // local half for next step
        __hip_atomic_store(&xmy[(st & 1) * 64 + (tid >> 1)], p,
                           __ATOMIC_RELAXED, __HIP_MEMORY_SCOPE_AGENT);
      }
    }
    __syncthreads();                     // drain stores before flag

    if (tid == 0) {
      __hip_atomic_fetch_add(&flags[myflag], 1, __ATOMIC_RELEASE,
                             __HIP_MEMORY_SCOPE_AGENT);
      int spin = 0;
      while (__hip_atomic_load(&flags[pflag], __ATOMIC_ACQUIRE,
                               __HIP_MEMORY_SCOPE_AGENT) < st + 1) {
        if (++spin > (1 << 18)) break;   // fail loudly, never hang
      }
    }
    __syncthreads();

    if (tid < 64) {                      // pull partner half
      u32 rp = __hip_atomic_load(&xpr[(st & 1) * 64 + tid],
                                 __ATOMIC_RELAXED, __HIP_MEMORY_SCOPE_AGENT);
      hp[(1 - side) * 64 + tid] = rp;
    }
    __syncthreads();
    xzu = xzun;
    tt = ttn;
  }
}

// ---------------- K3: logits = hcat @ dense_W + dense_b ----------------
__global__ __launch_bounds__(256) void dense_k(
    const float* __restrict__ hcat, const float* __restrict__ W,
    const float* __restrict__ bias, float* __restrict__ out)
{
  const int lane = threadIdx.x & 63;
  const int wv = threadIdx.x >> 6;
  const int rowbase = (blockIdx.x * 4 + wv) * 8;
  for (int rr = 0; rr < 8; ++rr) {
    const int row = rowbase + rr;
    const float* __restrict__ hr = hcat + (size_t)row * 512;
    float hv[8];
#pragma unroll
    for (int i = 0; i < 8; ++i) hv[i] = hr[i * 64 + lane];
    float myout = 0.f;
#pragma unroll
    for (int cc = 0; cc < 9; ++cc) {
      float p = 0.f;
#pragma unroll
      for (int i = 0; i < 8; ++i)
        p = fmaf(hv[i], W[(size_t)(i * 64 + lane) * 9 + cc], p);
#pragma unroll
      for (int o = 32; o > 0; o >>= 1) p += __shfl_xor(p, o);
      if (lane == cc) myout = p + bias[cc];
    }
    if (lane < 9) out[(size_t)row * 9 + lane] = myout;
  }
}

// ---------------- K4: CRF log-likelihood + trans copy ----------------
__global__ __launch_bounds__(64) void crf_k(
    const float* __restrict__ logits, const int* __restrict__ tags,
    const int* __restrict__ lengths, const float* __restrict__ trans,
    float* __restrict__ out_ll, float* __restrict__ out_trans)
{
  const int b = blockIdx.x;
  const int lane = threadIdx.x;
  const int len = lengths[b];
  const float* __restrict__ lg = logits + (size_t)b * TSEQ * NCLS;
  const int* __restrict__ tg = tags + (size_t)b * TSEQ;

  float ua = 0.f, ba = 0.f;
  for (int t = lane; t < TSEQ; t += 64) {
    int tag = tg[t];
    if (t < len) ua += lg[t * 9 + tag];
    if (t < len - 1) ba += trans[tag * 9 + tg[t + 1]];
  }
  float s = ua + ba;
#pragma unroll
  for (int o = 32; o > 0; o >>= 1) s += __shfl_xor(s, o);

  // alpha recursion: lane j owns class j (lanes >=9 compute dummies)
  const int j = (lane < 9) ? lane : 0;
  float trc[9], alpha[9];
#pragma unroll
  for (int i = 0; i < 9; ++i) trc[i] = trans[i * 9 + j];
#pragma unroll
  for (int i = 0; i < 9; ++i) alpha[i] = lg[i];
  for (int t = 1; t < TSEQ; ++t) {
    if (t >= len) break;                 // mask is monotone
    float m = -1e30f;
#pragma unroll
    for (int i = 0; i < 9; ++i) m = fmaxf(m, alpha[i] + trc[i]);
    float ss = 0.f;
#pragma unroll
    for (int i = 0; i < 9; ++i) ss += __expf(alpha[i] + trc[i] - m);
    float nj = __logf(ss) + m + lg[t * 9 + j];
#pragma unroll
    for (int i = 0; i < 9; ++i) alpha[i] = __shfl(nj, i);
  }
  float m2 = -1e30f;
#pragma unroll
  for (int i = 0; i < 9; ++i) m2 = fmaxf(m2, alpha[i]);
  float s2 = 0.f;
#pragma unroll
  for (int i = 0; i < 9; ++i) s2 += __expf(alpha[i] - m2);
  float lse = __logf(s2) + m2;
  if (lane == 0) out_ll[b] = s - lse;
  if (b == 0)
    for (int i = lane; i < 81; i += 64) out_trans[i] = trans[i];
}

// ---------------- launch ----------------
extern "C" void kernel_launch(void* const* d_in, const int* in_sizes, int n_in,
                              void* d_out, int out_size, void* d_ws, size_t ws_size,
                              hipStream_t stream)
{
  const int*   inputs  = (const int*)d_in[0];
  const int*   lengths = (const int*)d_in[1];
  const int*   targets = (const int*)d_in[2];
  const float* emb     = (const float*)d_in[3];
  const float* Wk_f    = (const float*)d_in[4];
  const float* Wr_f    = (const float*)d_in[5];
  const float* b_f     = (const float*)d_in[6];
  const float* Wk_b    = (const float*)d_in[7];
  const float* Wr_b    = (const float*)d_in[8];
  const float* b_b     = (const float*)d_in[9];
  const float* dense_W = (const float*)d_in[10];
  const float* dense_b = (const float*)d_in[11];
  const float* trans   = (const float*)d_in[12];

  char* ws = (char*)d_ws;
  int*   flags = (int*)ws;                                   // 1 KB
  u32*   xchg  = (u32*)(ws + 1024);                          // 128 KB
  u16*   xz    = (u16*)(ws + 1024 + 131072);                 // 134,217,728 B
  float* hcat  = (float*)(ws + 1024 + 131072 + 134217728ull);// 67,108,864 B

  float* out_logits = (float*)d_out;
  float* out_ll     = out_logits + (size_t)BATCH * TSEQ * NCLS;
  float* out_trans  = out_ll + BATCH;

  hipLaunchKernelGGL(init_k, dim3(1), dim3(256), 0, stream, flags);
  hipLaunchKernelGGL(xz_gemm_k, dim3(16, 256), dim3(256), 0, stream,
                     inputs, emb, Wk_f, b_f, Wk_b, b_b, xz);
  hipLaunchKernelGGL(lstm_k, dim3(256), dim3(512), 0, stream,
                     xz, Wr_f, Wr_b, lengths, hcat, flags, xchg);
  hipLaunchKernelGGL(dense_k, dim3(1024), dim3(256), 0, stream,
                     hcat, dense_W, dense_b, out_logits);
  hipLaunchKernelGGL(crf_k, dim3(64), dim3(64), 0, stream,
                     out_logits, targets, lengths, trans, out_ll, out_trans);
}

// Round 2
// 1609.674 us; speedup vs baseline: 2.1909x; 2.1909x over previous
//
#include <hip/hip_runtime.h>
#include <cstdint>
#include <cstddef>

typedef unsigned int  u32;
typedef unsigned short u16;
typedef _Float16 f16;
typedef _Float16 f16x2 __attribute__((ext_vector_type(2)));

#define BATCH 64
#define TSEQ  512
#define DEMB  300
#define HDIM  256
#define G4    1024
#define NCLS  9

__device__ __forceinline__ float fdot2(u32 a, u32 b, float c) {
#if __has_builtin(__builtin_amdgcn_fdot2)
  return __builtin_amdgcn_fdot2(__builtin_bit_cast(f16x2, a),
                                __builtin_bit_cast(f16x2, b), c, false);
#else
  f16x2 av = __builtin_bit_cast(f16x2, a), bv = __builtin_bit_cast(f16x2, b);
  return c + (float)av.x * (float)bv.x + (float)av.y * (float)bv.y;
#endif
}

__device__ __forceinline__ u32 packf16(float a, float b) {
  f16x2 v; v.x = (f16)a; v.y = (f16)b;
  return __builtin_bit_cast(u32, v);
}

__device__ __forceinline__ float sigm_fast(float x) {
  return __builtin_amdgcn_rcpf(1.f + __expf(-x));
}
__device__ __forceinline__ float tanh_fast(float x) {
  float ax = __builtin_fabsf(x);
  float e = __expf(-2.f * ax);
  float t = (1.f - e) * __builtin_amdgcn_rcpf(1.f + e);
  return copysignf(t, x);
}

// ---------------- K1: xz = emb[inputs] @ Wk + b  (f16 dot2 GEMM) ----------------
// M = B*T = 32768, K = 300, N = 2048 (cols 0..1023 fwd, 1024..2047 bwd)
__global__ __launch_bounds__(256) void xz_gemm_k(
    const int* __restrict__ inputs, const float* __restrict__ emb,
    const float* __restrict__ Wk_f, const float* __restrict__ b_f,
    const float* __restrict__ Wk_b, const float* __restrict__ b_b,
    u16* __restrict__ xz)
{
  __shared__ f16 As[10][128][2];   // [k-pair][row][parity]
  __shared__ f16 Bs[10][128][2];   // [k-pair][col][parity]
  const int tid = threadIdx.x;
  const int cb  = blockIdx.x * 128;      // 0..1920
  const int rb  = blockIdx.y * 128;
  const int dir = cb >> 10;
  const int cb1 = cb & 1023;
  const float* __restrict__ Wk   = dir ? Wk_b : Wk_f;
  const float* __restrict__ bias = dir ? b_b : b_f;
  const int tx = tid & 15, ty = tid >> 4;
  float acc[8][8];
#pragma unroll
  for (int i = 0; i < 8; ++i)
#pragma unroll
    for (int s = 0; s < 8; ++s) acc[i][s] = 0.f;

  for (int kt = 0; kt < 15; ++kt) {      // 15 * 20 = 300
    const int k0 = kt * 20;
#pragma unroll
    for (int i = 0; i < 10; ++i) {       // stage A: 128 rows x 20 k
      int e = tid * 10 + i;
      int r = e / 20, kk = e - r * 20;
      int v = inputs[rb + r];
      As[kk >> 1][r][kk & 1] = (f16)emb[(size_t)v * DEMB + k0 + kk];
    }
#pragma unroll
    for (int i = 0; i < 10; ++i) {       // stage B: 20 k x 128 cols
      int e = i * 256 + tid;
      int kk = e >> 7, c = e & 127;
      Bs[kk >> 1][c][kk & 1] = (f16)Wk[(size_t)(k0 + kk) * G4 + cb1 + c];
    }
    __syncthreads();
#pragma unroll
    for (int j = 0; j < 10; ++j) {
      u32 a2[8], b2[8];
#pragma unroll
      for (int i = 0; i < 8; ++i) a2[i] = *(const u32*)&As[j][ty * 8 + i][0];
#pragma unroll
      for (int s = 0; s < 8; ++s) b2[s] = *(const u32*)&Bs[j][s * 16 + tx][0];
#pragma unroll
      for (int i = 0; i < 8; ++i)
#pragma unroll
        for (int s = 0; s < 8; ++s)
          acc[i][s] = fdot2(a2[i], b2[s], acc[i][s]);
    }
    __syncthreads();
  }
#pragma unroll
  for (int i = 0; i < 8; ++i) {
    const int row = rb + ty * 8 + i;     // row = batch*512 + t
#pragma unroll
    for (int s = 0; s < 8; ++s) {
      const int col = cb1 + s * 16 + tx;
      float v = acc[i][s] + bias[col];
      f16 hv = (f16)v;
      xz[((size_t)dir * BATCH * TSEQ + row) * G4 + col] = __builtin_bit_cast(u16, hv);
    }
  }
}

// ---------------- K2: LSTM recurrence — one block per chain, zero inter-block sync ----
// 128 blocks x 512 threads. Thread owns gate columns c0=tid, c1=512+tid.
// Wr (512 KB f16-packed): 192 u32/thread in VGPRs + 128 KB in LDS.
__global__ __launch_bounds__(512, 1) void lstm_k(
    const u16* __restrict__ xz, const float* __restrict__ Wr_f,
    const float* __restrict__ Wr_b, const int* __restrict__ lengths,
    float* __restrict__ hcat)
{
  const int chain = blockIdx.x;
  const int dir   = chain >> 6;
  const int batch = chain & 63;
  const int tid = threadIdx.x;
  const float* __restrict__ Wr = dir ? Wr_b : Wr_f;

  __shared__ __align__(16) u32 wlds[16][512][4];  // 128 KB: c1 weights, k-pairs 64..127
  __shared__ __align__(16) u32 hp[128];           // packed h(t-1), f16x2
  __shared__ float zbuf[1024];

  const int c0 = tid, c1 = 512 + tid;
  u32 w0r[128];                          // c0 weights, k-pairs 0..127
  u32 w1r[64];                           // c1 weights, k-pairs 0..63
#pragma unroll
  for (int j = 0; j < 128; ++j)
    w0r[j] = packf16(Wr[(size_t)(2 * j) * G4 + c0],
                     Wr[(size_t)(2 * j + 1) * G4 + c0]);
#pragma unroll
  for (int j = 0; j < 64; ++j)
    w1r[j] = packf16(Wr[(size_t)(2 * j) * G4 + c1],
                     Wr[(size_t)(2 * j + 1) * G4 + c1]);
#pragma unroll
  for (int g = 0; g < 16; ++g)
#pragma unroll
    for (int u = 0; u < 4; ++u) {
      int kp = 64 + g * 4 + u;
      wlds[g][tid][u] = packf16(Wr[(size_t)(2 * kp) * G4 + c1],
                                Wr[(size_t)(2 * kp + 1) * G4 + c1]);
    }
  if (tid < 128) hp[tid] = 0u;

  float c = 0.f, h = 0.f;
  const int len = lengths[batch];
  const u16* __restrict__ xzb = xz + (size_t)(dir * BATCH + batch) * TSEQ * G4;
  float* __restrict__ hrow = hcat + (size_t)batch * TSEQ * 512 + dir * 256;
  __syncthreads();

  int tt = dir ? (TSEQ - 1) : 0;
  const int ttstep = dir ? -1 : 1;
  u16 x0 = xzb[(size_t)tt * G4 + c0];
  u16 x1 = xzb[(size_t)tt * G4 + c1];

  for (int st = 0; st < TSEQ; ++st) {
    const int ttn = (st == TSEQ - 1) ? tt : tt + ttstep;
    u16 x0n = xzb[(size_t)ttn * G4 + c0];  // prefetch next step's xz
    u16 x1n = xzb[(size_t)ttn * G4 + c1];

    float a0 = (float)__builtin_bit_cast(f16, x0);
    float a1 = (float)__builtin_bit_cast(f16, x1);
#pragma unroll
    for (int g = 0; g < 16; ++g) {         // k-pairs 0..63 (both cols from VGPR)
      uint4 h4 = *(const uint4*)&hp[g * 4];
      a0 = fdot2(w0r[g * 4 + 0], h4.x, a0); a1 = fdot2(w1r[g * 4 + 0], h4.x, a1);
      a0 = fdot2(w0r[g * 4 + 1], h4.y, a0); a1 = fdot2(w1r[g * 4 + 1], h4.y, a1);
      a0 = fdot2(w0r[g * 4 + 2], h4.z, a0); a1 = fdot2(w1r[g * 4 + 2], h4.z, a1);
      a0 = fdot2(w0r[g * 4 + 3], h4.w, a0); a1 = fdot2(w1r[g * 4 + 3], h4.w, a1);
    }
#pragma unroll
    for (int g = 0; g < 16; ++g) {         // k-pairs 64..127 (c1 from LDS)
      uint4 h4 = *(const uint4*)&hp[64 + g * 4];
      uint4 wl = *(const uint4*)&wlds[g][tid][0];
      a0 = fdot2(w0r[64 + g * 4 + 0], h4.x, a0); a1 = fdot2(wl.x, h4.x, a1);
      a0 = fdot2(w0r[64 + g * 4 + 1], h4.y, a0); a1 = fdot2(wl.y, h4.y, a1);
      a0 = fdot2(w0r[64 + g * 4 + 2], h4.z, a0); a1 = fdot2(wl.z, h4.z, a1);
      a0 = fdot2(w0r[64 + g * 4 + 3], h4.w, a0); a1 = fdot2(wl.w, h4.w, a1);
    }
    zbuf[c0] = a0;
    zbuf[c1] = a1;
    __syncthreads();

    if (tid < 256) {                       // waves 0-3: combine gates for k = tid
      float zi = zbuf[tid], zf = zbuf[256 + tid];
      float zg = zbuf[512 + tid], zo = zbuf[768 + tid];
      float ig = sigm_fast(zi);
      float fg = sigm_fast(zf);
      float gg = tanh_fast(zg);
      float og = sigm_fast(zo);
      float cn = fg * c + ig * gg;
      float hn = og * tanh_fast(cn);
      if (tt < len) { c = cn; h = hn; }    // masked step: hold state
      hrow[(size_t)tt * 512 + tid] = h;    // fp32 h for dense layer
      float ho = __shfl_xor(h, 1);
      if (!(tid & 1)) hp[tid >> 1] = packf16(h, ho);
    }
    __syncthreads();
    x0 = x0n; x1 = x1n; tt = ttn;
  }
}

// ---------------- K3: logits = hcat @ dense_W + dense_b ----------------
__global__ __launch_bounds__(256) void dense_k(
    const float* __restrict__ hcat, const float* __restrict__ W,
    const float* __restrict__ bias, float* __restrict__ out)
{
  const int lane = threadIdx.x & 63;
  const int wv = threadIdx.x >> 6;
  const int rowbase = (blockIdx.x * 4 + wv) * 8;
  for (int rr = 0; rr < 8; ++rr) {
    const int row = rowbase + rr;
    const float* __restrict__ hr = hcat + (size_t)row * 512;
    float hv[8];
#pragma unroll
    for (int i = 0; i < 8; ++i) hv[i] = hr[i * 64 + lane];
    float myout = 0.f;
#pragma unroll
    for (int cc = 0; cc < 9; ++cc) {
      float p = 0.f;
#pragma unroll
      for (int i = 0; i < 8; ++i)
        p = fmaf(hv[i], W[(size_t)(i * 64 + lane) * 9 + cc], p);
#pragma unroll
      for (int o = 32; o > 0; o >>= 1) p += __shfl_xor(p, o);
      if (lane == cc) myout = p + bias[cc];
    }
    if (lane < 9) out[(size_t)row * 9 + lane] = myout;
  }
}

// ---------------- K4: CRF log-likelihood + trans copy ----------------
__global__ __launch_bounds__(64) void crf_k(
    const float* __restrict__ logits, const int* __restrict__ tags,
    const int* __restrict__ lengths, const float* __restrict__ trans,
    float* __restrict__ out_ll, float* __restrict__ out_trans)
{
  const int b = blockIdx.x;
  const int lane = threadIdx.x;
  const int len = lengths[b];
  const float* __restrict__ lg = logits + (size_t)b * TSEQ * NCLS;
  const int* __restrict__ tg = tags + (size_t)b * TSEQ;

  float ua = 0.f, ba = 0.f;
  for (int t = lane; t < TSEQ; t += 64) {
    int tag = tg[t];
    if (t < len) ua += lg[t * 9 + tag];
    if (t < len - 1) ba += trans[tag * 9 + tg[t + 1]];
  }
  float s = ua + ba;
#pragma unroll
  for (int o = 32; o > 0; o >>= 1) s += __shfl_xor(s, o);

  // alpha recursion: lane j owns class j (lanes >=9 compute dummies)
  const int j = (lane < 9) ? lane : 0;
  float trc[9], alpha[9];
#pragma unroll
  for (int i = 0; i < 9; ++i) trc[i] = trans[i * 9 + j];
#pragma unroll
  for (int i = 0; i < 9; ++i) alpha[i] = lg[i];
  for (int t = 1; t < TSEQ; ++t) {
    if (t >= len) break;                 // mask is monotone
    float m = -1e30f;
#pragma unroll
    for (int i = 0; i < 9; ++i) m = fmaxf(m, alpha[i] + trc[i]);
    float ss = 0.f;
#pragma unroll
    for (int i = 0; i < 9; ++i) ss += __expf(alpha[i] + trc[i] - m);
    float nj = __logf(ss) + m + lg[t * 9 + j];
#pragma unroll
    for (int i = 0; i < 9; ++i) alpha[i] = __shfl(nj, i);
  }
  float m2 = -1e30f;
#pragma unroll
  for (int i = 0; i < 9; ++i) m2 = fmaxf(m2, alpha[i]);
  float s2 = 0.f;
#pragma unroll
  for (int i = 0; i < 9; ++i) s2 += __expf(alpha[i] - m2);
  float lse = __logf(s2) + m2;
  if (lane == 0) out_ll[b] = s - lse;
  if (b == 0)
    for (int i = lane; i < 81; i += 64) out_trans[i] = trans[i];
}

// ---------------- launch ----------------
extern "C" void kernel_launch(void* const* d_in, const int* in_sizes, int n_in,
                              void* d_out, int out_size, void* d_ws, size_t ws_size,
                              hipStream_t stream)
{
  const int*   inputs  = (const int*)d_in[0];
  const int*   lengths = (const int*)d_in[1];
  const int*   targets = (const int*)d_in[2];
  const float* emb     = (const float*)d_in[3];
  const float* Wk_f    = (const float*)d_in[4];
  const float* Wr_f    = (const float*)d_in[5];
  const float* b_f     = (const float*)d_in[6];
  const float* Wk_b    = (const float*)d_in[7];
  const float* Wr_b    = (const float*)d_in[8];
  const float* b_b     = (const float*)d_in[9];
  const float* dense_W = (const float*)d_in[10];
  const float* dense_b = (const float*)d_in[11];
  const float* trans   = (const float*)d_in[12];

  char* ws = (char*)d_ws;
  u16*   xz   = (u16*)ws;                          // 134,217,728 B
  float* hcat = (float*)(ws + 134217728ull);       // 67,108,864 B

  float* out_logits = (float*)d_out;
  float* out_ll     = out_logits + (size_t)BATCH * TSEQ * NCLS;
  float* out_trans  = out_ll + BATCH;

  hipLaunchKernelGGL(xz_gemm_k, dim3(16, 256), dim3(256), 0, stream,
                     inputs, emb, Wk_f, b_f, Wk_b, b_b, xz);
  hipLaunchKernelGGL(lstm_k, dim3(128), dim3(512), 0, stream,
                     xz, Wr_f, Wr_b, lengths, hcat);
  hipLaunchKernelGGL(dense_k, dim3(1024), dim3(256), 0, stream,
                     hcat, dense_W, dense_b, out_logits);
  hipLaunchKernelGGL(crf_k, dim3(64), dim3(64), 0, stream,
                     out_logits, targets, lengths, trans, out_ll, out_trans);
}

// Round 3
// 1413.747 us; speedup vs baseline: 2.4946x; 1.1386x over previous
//
#include <hip/hip_runtime.h>
#include <cstdint>
#include <cstddef>

typedef unsigned int  u32;
typedef unsigned short u16;
typedef _Float16 f16;
typedef _Float16 f16x2 __attribute__((ext_vector_type(2)));
typedef _Float16 half8 __attribute__((ext_vector_type(8)));
typedef float    f32x4v __attribute__((ext_vector_type(4)));

#define BATCH 64
#define TSEQ  512
#define DEMB  300
#define KPAD  320
#define HDIM  256
#define G4    1024
#define NCLS  9

__device__ __forceinline__ float fdot2(u32 a, u32 b, float c) {
  return __builtin_amdgcn_fdot2(__builtin_bit_cast(f16x2, a),
                                __builtin_bit_cast(f16x2, b), c, false);
}
__device__ __forceinline__ u32 packf16(float a, float b) {
  f16x2 v; v.x = (f16)a; v.y = (f16)b;
  return __builtin_bit_cast(u32, v);
}
__device__ __forceinline__ float sigm_fast(float x) {
  return __builtin_amdgcn_rcpf(1.f + __expf(-x));
}
__device__ __forceinline__ float tanh_fast(float x) {
  float ax = __builtin_fabsf(x);
  float e = __expf(-2.f * ax);
  float t = (1.f - e) * __builtin_amdgcn_rcpf(1.f + e);
  return copysignf(t, x);
}

// ---------------- P1: embf16[v][320] = f16(emb[v][0..299]), zero-pad 300..319 ----
__global__ __launch_bounds__(256) void embcvt_k(const float* __restrict__ emb,
                                                u16* __restrict__ out) {
  const int v  = blockIdx.x * 16 + (threadIdx.x >> 4);
  const int kc = threadIdx.x & 15;
  u32* __restrict__ dst = (u32*)(out + (size_t)v * KPAD + kc * 20);
  if (kc < 15) {
    const float* __restrict__ src = emb + (size_t)v * DEMB + kc * 20;
    float tmp[20];
#pragma unroll
    for (int j = 0; j < 20; ++j) tmp[j] = src[j];
#pragma unroll
    for (int j = 0; j < 10; ++j) dst[j] = packf16(tmp[2 * j], tmp[2 * j + 1]);
  } else {
#pragma unroll
    for (int j = 0; j < 10; ++j) dst[j] = 0u;
  }
}

// ---------------- P2: wkt[dir][col][320] = f16(Wk[k][col]), zero-pad k>=300 -----
__global__ __launch_bounds__(256) void wkt_k(const float* __restrict__ Wk_f,
                                             const float* __restrict__ Wk_b,
                                             u16* __restrict__ wkt) {
  const int dir = blockIdx.y;
  const float* __restrict__ Wk = dir ? Wk_b : Wk_f;
  const int col = blockIdx.x * 16 + (threadIdx.x >> 4);
  const int kc  = threadIdx.x & 15;
  u32* __restrict__ dst = (u32*)(wkt + ((size_t)dir * G4 + col) * KPAD + kc * 20);
  if (kc < 15) {
    float tmp[20];
#pragma unroll
    for (int j = 0; j < 20; ++j) tmp[j] = Wk[(size_t)(kc * 20 + j) * G4 + col];
#pragma unroll
    for (int j = 0; j < 10; ++j) dst[j] = packf16(tmp[2 * j], tmp[2 * j + 1]);
  } else {
#pragma unroll
    for (int j = 0; j < 10; ++j) dst[j] = 0u;
  }
}

// ---------------- K1: xz = emb[inputs] @ Wk + b  (MFMA f16) ----------------
// A = wkt (m = gate col), B = gathered embf16 (n = emb row), K = 320.
// Block: 128 cols x 128 rows, 256 threads (4 waves); wave owns 32 rows.
__global__ __launch_bounds__(256) void xz_gemm_k(
    const int* __restrict__ inputs, const u16* __restrict__ wkt,
    const u16* __restrict__ embf16, const float* __restrict__ b_f,
    const float* __restrict__ b_b, u16* __restrict__ xz)
{
  __shared__ __align__(16) u16 As[128 * 40];   // [m][k], k-major, pad 32->40
  __shared__ __align__(16) u16 Bs[128 * 40];   // [n][k], k-major
  const int tid  = threadIdx.x;
  const int wv   = tid >> 6, lane = tid & 63;
  const int quad = lane >> 4, fl = lane & 15;
  const int cbi  = blockIdx.x;                 // 0..15
  const int dir  = cbi >> 3;
  const int cb1  = (cbi & 7) * 128;
  const int rb   = blockIdx.y * 128;
  const float* __restrict__ bias = dir ? b_b : b_f;

  const int sm = tid >> 1, sh = (tid & 1) * 16;          // staging row, k-half
  const int vrow = inputs[rb + sm];
  const u16* __restrict__ asrc = wkt + ((size_t)(dir * G4) + cb1 + sm) * KPAD + sh;
  const u16* __restrict__ bsrc = embf16 + (size_t)vrow * KPAD + sh;

  f32x4v acc[2][8];
#pragma unroll
  for (int bt = 0; bt < 2; ++bt)
#pragma unroll
    for (int i = 0; i < 8; ++i) acc[bt][i] = (f32x4v){0.f, 0.f, 0.f, 0.f};

  for (int kt = 0; kt < 10; ++kt) {
    const int k0 = kt * 32;
    uint4 a0v = *(const uint4*)(asrc + k0);
    uint4 a1v = *(const uint4*)(asrc + k0 + 8);
    uint4 b0v = *(const uint4*)(bsrc + k0);
    uint4 b1v = *(const uint4*)(bsrc + k0 + 8);
    *(uint4*)&As[sm * 40 + sh]     = a0v;
    *(uint4*)&As[sm * 40 + sh + 8] = a1v;
    *(uint4*)&Bs[sm * 40 + sh]     = b0v;
    *(uint4*)&Bs[sm * 40 + sh + 8] = b1v;
    __syncthreads();
    half8 bf[2];
#pragma unroll
    for (int bt = 0; bt < 2; ++bt)
      bf[bt] = *(const half8*)&Bs[(wv * 32 + bt * 16 + fl) * 40 + quad * 8];
#pragma unroll
    for (int i = 0; i < 8; ++i) {
      half8 af = *(const half8*)&As[(i * 16 + fl) * 40 + quad * 8];
      acc[0][i] = __builtin_amdgcn_mfma_f32_16x16x32_f16(af, bf[0], acc[0][i], 0, 0, 0);
      acc[1][i] = __builtin_amdgcn_mfma_f32_16x16x32_f16(af, bf[1], acc[1][i], 0, 0, 0);
    }
    __syncthreads();
  }
#pragma unroll
  for (int bt = 0; bt < 2; ++bt) {
    const int row = rb + wv * 32 + bt * 16 + fl;         // n = emb row
    u16* __restrict__ orow = xz + ((size_t)(dir * BATCH * TSEQ) + row) * G4;
#pragma unroll
    for (int i = 0; i < 8; ++i) {
      const int mb = cb1 + i * 16 + quad * 4;            // m = gate col (4 consecutive)
      const float4 bb = *(const float4*)&bias[mb];
      f32x4v v = acc[bt][i];
      uint2 pk;
      pk.x = packf16(v[0] + bb.x, v[1] + bb.y);
      pk.y = packf16(v[2] + bb.z, v[3] + bb.w);
      *(uint2*)&orow[mb] = pk;
    }
  }
}

// ---------------- K2: LSTM recurrence — one block per chain ----------------
// 128 blocks x 512 threads. Thread owns gate columns c0=tid, c1=512+tid.
// h(t-1) distributed via 1 ds_read_b64 + v_readlane (SGPR operand to fdot2),
// replacing 32 broadcast ds_read_b128 per thread per step.
__global__ __launch_bounds__(512, 1) void lstm_k(
    const u16* __restrict__ xz, const float* __restrict__ Wr_f,
    const float* __restrict__ Wr_b, const int* __restrict__ lengths,
    u16* __restrict__ hcat)
{
  const int chain = blockIdx.x;
  const int dir   = chain >> 6;
  const int batch = chain & 63;
  const int tid = threadIdx.x;
  const float* __restrict__ Wr = dir ? Wr_b : Wr_f;

  __shared__ __align__(16) u32 wlds[16][512][4];  // 128 KB: c1 weights, k-pairs 64..127
  __shared__ __align__(16) u32 hp[128];           // packed h(t-1), f16x2
  __shared__ float zbuf[1024];

  const int c0 = tid, c1 = 512 + tid;
  u32 w0r[128];                          // c0 weights, k-pairs 0..127
  u32 w1r[64];                           // c1 weights, k-pairs 0..63
#pragma unroll
  for (int j = 0; j < 128; ++j)
    w0r[j] = packf16(Wr[(size_t)(2 * j) * G4 + c0],
                     Wr[(size_t)(2 * j + 1) * G4 + c0]);
#pragma unroll
  for (int j = 0; j < 64; ++j)
    w1r[j] = packf16(Wr[(size_t)(2 * j) * G4 + c1],
                     Wr[(size_t)(2 * j + 1) * G4 + c1]);
#pragma unroll
  for (int g = 0; g < 16; ++g)
#pragma unroll
    for (int u = 0; u < 4; ++u) {
      int kp = 64 + g * 4 + u;
      wlds[g][tid][u] = packf16(Wr[(size_t)(2 * kp) * G4 + c1],
                                Wr[(size_t)(2 * kp + 1) * G4 + c1]);
    }
  if (tid < 128) hp[tid] = 0u;

  float c = 0.f, h = 0.f;
  const int len = lengths[batch];
  const u16* __restrict__ xzb = xz + (size_t)(dir * BATCH + batch) * TSEQ * G4;
  u16* __restrict__ hrow = hcat + (size_t)batch * TSEQ * 512 + dir * 256;
  const int lane = tid & 63;
  __syncthreads();

  int tt = dir ? (TSEQ - 1) : 0;
  const int ttstep = dir ? -1 : 1;
  u16 x0 = xzb[(size_t)tt * G4 + c0];
  u16 x1 = xzb[(size_t)tt * G4 + c1];

  for (int st = 0; st < TSEQ; ++st) {
    const int ttn = (st == TSEQ - 1) ? tt : tt + ttstep;
    u16 x0n = xzb[(size_t)ttn * G4 + c0];  // prefetch next step's xz
    u16 x1n = xzb[(size_t)ttn * G4 + c1];

    // lane L holds hp[2L], hp[2L+1]; readlane broadcasts via SGPRs
    const uint2 hv2 = *(const uint2*)&hp[lane * 2];

    float a0 = (float)__builtin_bit_cast(f16, x0);
    float a1 = (float)__builtin_bit_cast(f16, x1);
#pragma unroll
    for (int j = 0; j < 32; ++j) {         // k-pairs 0..63: both cols from VGPR
      u32 s0 = (u32)__builtin_amdgcn_readlane((int)hv2.x, j);
      u32 s1 = (u32)__builtin_amdgcn_readlane((int)hv2.y, j);
      a0 = fdot2(w0r[2 * j], s0, a0);     a0 = fdot2(w0r[2 * j + 1], s1, a0);
      a1 = fdot2(w1r[2 * j], s0, a1);     a1 = fdot2(w1r[2 * j + 1], s1, a1);
    }
#pragma unroll
    for (int g = 0; g < 16; ++g) {         // k-pairs 64..127: c1 weights from LDS
      uint4 wl = *(const uint4*)&wlds[g][tid][0];
      const int j = 32 + 2 * g;
      u32 s0 = (u32)__builtin_amdgcn_readlane((int)hv2.x, j);
      u32 s1 = (u32)__builtin_amdgcn_readlane((int)hv2.y, j);
      a0 = fdot2(w0r[2 * j], s0, a0);     a0 = fdot2(w0r[2 * j + 1], s1, a0);
      a1 = fdot2(wl.x, s0, a1);           a1 = fdot2(wl.y, s1, a1);
      u32 s2 = (u32)__builtin_amdgcn_readlane((int)hv2.x, j + 1);
      u32 s3 = (u32)__builtin_amdgcn_readlane((int)hv2.y, j + 1);
      a0 = fdot2(w0r[2 * j + 2], s2, a0); a0 = fdot2(w0r[2 * j + 3], s3, a0);
      a1 = fdot2(wl.z, s2, a1);           a1 = fdot2(wl.w, s3, a1);
    }
    zbuf[c0] = a0;
    zbuf[c1] = a1;
    __syncthreads();

    if (tid < 256) {                       // waves 0-3: combine gates for k = tid
      float zi = zbuf[tid], zf = zbuf[256 + tid];
      float zg = zbuf[512 + tid], zo = zbuf[768 + tid];
      float ig = sigm_fast(zi);
      float fg = sigm_fast(zf);
      float gg = tanh_fast(zg);
      float og = sigm_fast(zo);
      float cn = fg * c + ig * gg;
      float hn = og * tanh_fast(cn);
      if (tt < len) { c = cn; h = hn; }    // masked step: hold state
      u32 hbits = packf16(h, h);
      hrow[(size_t)tt * 512 + tid] = (u16)(hbits & 0xffffu);  // f16 h for dense
      float ho = __shfl_xor(h, 1);
      if (!(tid & 1)) hp[tid >> 1] = packf16(h, ho);
    }
    __syncthreads();
    x0 = x0n; x1 = x1n; tt = ttn;
  }
}

// ---------------- K3: logits = hcat @ dense_W + dense_b ----------------
__global__ __launch_bounds__(256) void dense_k(
    const u16* __restrict__ hcat, const float* __restrict__ W,
    const float* __restrict__ bias, float* __restrict__ out)
{
  const int lane = threadIdx.x & 63;
  const int wv = threadIdx.x >> 6;
  const int rowbase = (blockIdx.x * 4 + wv) * 8;
  for (int rr = 0; rr < 8; ++rr) {
    const int row = rowbase + rr;
    const u16* __restrict__ hr = hcat + (size_t)row * 512;
    float hv[8];
#pragma unroll
    for (int i = 0; i < 8; ++i)
      hv[i] = (float)__builtin_bit_cast(f16, hr[i * 64 + lane]);
    float myout = 0.f;
#pragma unroll
    for (int cc = 0; cc < 9; ++cc) {
      float p = 0.f;
#pragma unroll
      for (int i = 0; i < 8; ++i)
        p = fmaf(hv[i], W[(size_t)(i * 64 + lane) * 9 + cc], p);
#pragma unroll
      for (int o = 32; o > 0; o >>= 1) p += __shfl_xor(p, o);
      if (lane == cc) myout = p + bias[cc];
    }
    if (lane < 9) out[(size_t)row * 9 + lane] = myout;
  }
}

// ---------------- K4: CRF log-likelihood + trans copy ----------------
__global__ __launch_bounds__(64) void crf_k(
    const float* __restrict__ logits, const int* __restrict__ tags,
    const int* __restrict__ lengths, const float* __restrict__ trans,
    float* __restrict__ out_ll, float* __restrict__ out_trans)
{
  const int b = blockIdx.x;
  const int lane = threadIdx.x;
  const int len = lengths[b];
  const float* __restrict__ lg = logits + (size_t)b * TSEQ * NCLS;
  const int* __restrict__ tg = tags + (size_t)b * TSEQ;

  float ua = 0.f, ba = 0.f;
  for (int t = lane; t < TSEQ; t += 64) {
    int tag = tg[t];
    if (t < len) ua += lg[t * 9 + tag];
    if (t < len - 1) ba += trans[tag * 9 + tg[t + 1]];
  }
  float s = ua + ba;
#pragma unroll
  for (int o = 32; o > 0; o >>= 1) s += __shfl_xor(s, o);

  const int j = (lane < 9) ? lane : 0;
  float trc[9], alpha[9];
#pragma unroll
  for (int i = 0; i < 9; ++i) trc[i] = trans[i * 9 + j];
#pragma unroll
  for (int i = 0; i < 9; ++i) alpha[i] = lg[i];
  for (int t = 1; t < TSEQ; ++t) {
    if (t >= len) break;                 // mask is monotone
    float m = -1e30f;
#pragma unroll
    for (int i = 0; i < 9; ++i) m = fmaxf(m, alpha[i] + trc[i]);
    float ss = 0.f;
#pragma unroll
    for (int i = 0; i < 9; ++i) ss += __expf(alpha[i] + trc[i] - m);
    float nj = __logf(ss) + m + lg[t * 9 + j];
#pragma unroll
    for (int i = 0; i < 9; ++i) alpha[i] = __shfl(nj, i);
  }
  float m2 = -1e30f;
#pragma unroll
  for (int i = 0; i < 9; ++i) m2 = fmaxf(m2, alpha[i]);
  float s2 = 0.f;
#pragma unroll
  for (int i = 0; i < 9; ++i) s2 += __expf(alpha[i] - m2);
  float lse = __logf(s2) + m2;
  if (lane == 0) out_ll[b] = s - lse;
  if (b == 0)
    for (int i = lane; i < 81; i += 64) out_trans[i] = trans[i];
}

// ---------------- launch ----------------
extern "C" void kernel_launch(void* const* d_in, const int* in_sizes, int n_in,
                              void* d_out, int out_size, void* d_ws, size_t ws_size,
                              hipStream_t stream)
{
  const int*   inputs  = (const int*)d_in[0];
  const int*   lengths = (const int*)d_in[1];
  const int*   targets = (const int*)d_in[2];
  const float* emb     = (const float*)d_in[3];
  const float* Wk_f    = (const float*)d_in[4];
  const float* Wr_f    = (const float*)d_in[5];
  const float* Wk_b    = (const float*)d_in[7];
  const float* Wr_b    = (const float*)d_in[8];
  const float* b_f     = (const float*)d_in[6];
  const float* b_b     = (const float*)d_in[9];
  const float* dense_W = (const float*)d_in[10];
  const float* dense_b = (const float*)d_in[11];
  const float* trans   = (const float*)d_in[12];

  char* ws = (char*)d_ws;
  u16* wkt    = (u16*)ws;                                    //  1,310,720 B
  u16* embf16 = (u16*)(ws + 1310720ull);                     // 19,200,000 B
  u16* xz     = (u16*)(ws + 1310720ull + 19200000ull);       // 134,217,728 B
  u16* hcat   = (u16*)(ws + 1310720ull + 19200000ull + 134217728ull); // 33,554,432 B

  float* out_logits = (float*)d_out;
  float* out_ll     = out_logits + (size_t)BATCH * TSEQ * NCLS;
  float* out_trans  = out_ll + BATCH;

  hipLaunchKernelGGL(embcvt_k, dim3(1875), dim3(256), 0, stream, emb, embf16);
  hipLaunchKernelGGL(wkt_k, dim3(64, 2), dim3(256), 0, stream, Wk_f, Wk_b, wkt);
  hipLaunchKernelGGL(xz_gemm_k, dim3(16, 256), dim3(256), 0, stream,
                     inputs, wkt, embf16, b_f, b_b, xz);
  hipLaunchKernelGGL(lstm_k, dim3(128), dim3(512), 0, stream,
                     xz, Wr_f, Wr_b, lengths, hcat);
  hipLaunchKernelGGL(dense_k, dim3(1024), dim3(256), 0, stream,
                     hcat, dense_W, dense_b, out_logits);
  hipLaunchKernelGGL(crf_k, dim3(64), dim3(64), 0, stream,
                     out_logits, targets, lengths, trans, out_ll, out_trans);
}

// Round 4
// 1412.106 us; speedup vs baseline: 2.4975x; 1.0012x over previous
//
#include <hip/hip_runtime.h>
#include <cstdint>
#include <cstddef>

typedef unsigned int  u32;
typedef unsigned short u16;
typedef _Float16 f16;
typedef _Float16 f16x2 __attribute__((ext_vector_type(2)));
typedef _Float16 half8 __attribute__((ext_vector_type(8)));
typedef float    f32x4v __attribute__((ext_vector_type(4)));

#define BATCH 64
#define TSEQ  512
#define DEMB  300
#define KPAD  320
#define HDIM  256
#define G4    1024
#define NCLS  9

__device__ __forceinline__ float fdot2(u32 a, u32 b, float c) {
  return __builtin_amdgcn_fdot2(__builtin_bit_cast(f16x2, a),
                                __builtin_bit_cast(f16x2, b), c, false);
}
__device__ __forceinline__ u32 packf16(float a, float b) {
  f16x2 v; v.x = (f16)a; v.y = (f16)b;
  return __builtin_bit_cast(u32, v);
}
__device__ __forceinline__ float sigm_fast(float x) {
  return __builtin_amdgcn_rcpf(1.f + __expf(-x));
}
__device__ __forceinline__ float tanh_fast(float x) {
  float ax = __builtin_fabsf(x);
  float e = __expf(-2.f * ax);
  float t = (1.f - e) * __builtin_amdgcn_rcpf(1.f + e);
  return copysignf(t, x);
}

// ---------------- P1: embf16[v][320] = f16(emb[v][0..299]), zero-pad 300..319 ----
__global__ __launch_bounds__(256) void embcvt_k(const float* __restrict__ emb,
                                                u16* __restrict__ out) {
  const int v  = blockIdx.x * 16 + (threadIdx.x >> 4);
  const int kc = threadIdx.x & 15;
  u32* __restrict__ dst = (u32*)(out + (size_t)v * KPAD + kc * 20);
  if (kc < 15) {
    const float* __restrict__ src = emb + (size_t)v * DEMB + kc * 20;
    float tmp[20];
#pragma unroll
    for (int j = 0; j < 20; ++j) tmp[j] = src[j];
#pragma unroll
    for (int j = 0; j < 10; ++j) dst[j] = packf16(tmp[2 * j], tmp[2 * j + 1]);
  } else {
#pragma unroll
    for (int j = 0; j < 10; ++j) dst[j] = 0u;
  }
}

// ---------------- P2: wkt[dir][col][320] = f16(Wk[k][col]), zero-pad k>=300 -----
__global__ __launch_bounds__(256) void wkt_k(const float* __restrict__ Wk_f,
                                             const float* __restrict__ Wk_b,
                                             u16* __restrict__ wkt) {
  const int dir = blockIdx.y;
  const float* __restrict__ Wk = dir ? Wk_b : Wk_f;
  const int col = blockIdx.x * 16 + (threadIdx.x >> 4);
  const int kc  = threadIdx.x & 15;
  u32* __restrict__ dst = (u32*)(wkt + ((size_t)dir * G4 + col) * KPAD + kc * 20);
  if (kc < 15) {
    float tmp[20];
#pragma unroll
    for (int j = 0; j < 20; ++j) tmp[j] = Wk[(size_t)(kc * 20 + j) * G4 + col];
#pragma unroll
    for (int j = 0; j < 10; ++j) dst[j] = packf16(tmp[2 * j], tmp[2 * j + 1]);
  } else {
#pragma unroll
    for (int j = 0; j < 10; ++j) dst[j] = 0u;
  }
}

// ---------------- K1: xz = emb[inputs] @ Wk + b  (MFMA f16) ----------------
__global__ __launch_bounds__(256) void xz_gemm_k(
    const int* __restrict__ inputs, const u16* __restrict__ wkt,
    const u16* __restrict__ embf16, const float* __restrict__ b_f,
    const float* __restrict__ b_b, u16* __restrict__ xz)
{
  __shared__ __align__(16) u16 As[128 * 40];   // [m][k], k-major, pad 32->40
  __shared__ __align__(16) u16 Bs[128 * 40];   // [n][k], k-major
  const int tid  = threadIdx.x;
  const int wv   = tid >> 6, lane = tid & 63;
  const int quad = lane >> 4, fl = lane & 15;
  const int cbi  = blockIdx.x;                 // 0..15
  const int dir  = cbi >> 3;
  const int cb1  = (cbi & 7) * 128;
  const int rb   = blockIdx.y * 128;
  const float* __restrict__ bias = dir ? b_b : b_f;

  const int sm = tid >> 1, sh = (tid & 1) * 16;          // staging row, k-half
  const int vrow = inputs[rb + sm];
  const u16* __restrict__ asrc = wkt + ((size_t)(dir * G4) + cb1 + sm) * KPAD + sh;
  const u16* __restrict__ bsrc = embf16 + (size_t)vrow * KPAD + sh;

  f32x4v acc[2][8];
#pragma unroll
  for (int bt = 0; bt < 2; ++bt)
#pragma unroll
    for (int i = 0; i < 8; ++i) acc[bt][i] = (f32x4v){0.f, 0.f, 0.f, 0.f};

  for (int kt = 0; kt < 10; ++kt) {
    const int k0 = kt * 32;
    uint4 a0v = *(const uint4*)(asrc + k0);
    uint4 a1v = *(const uint4*)(asrc + k0 + 8);
    uint4 b0v = *(const uint4*)(bsrc + k0);
    uint4 b1v = *(const uint4*)(bsrc + k0 + 8);
    *(uint4*)&As[sm * 40 + sh]     = a0v;
    *(uint4*)&As[sm * 40 + sh + 8] = a1v;
    *(uint4*)&Bs[sm * 40 + sh]     = b0v;
    *(uint4*)&Bs[sm * 40 + sh + 8] = b1v;
    __syncthreads();
    half8 bf[2];
#pragma unroll
    for (int bt = 0; bt < 2; ++bt)
      bf[bt] = *(const half8*)&Bs[(wv * 32 + bt * 16 + fl) * 40 + quad * 8];
#pragma unroll
    for (int i = 0; i < 8; ++i) {
      half8 af = *(const half8*)&As[(i * 16 + fl) * 40 + quad * 8];
      acc[0][i] = __builtin_amdgcn_mfma_f32_16x16x32_f16(af, bf[0], acc[0][i], 0, 0, 0);
      acc[1][i] = __builtin_amdgcn_mfma_f32_16x16x32_f16(af, bf[1], acc[1][i], 0, 0, 0);
    }
    __syncthreads();
  }
#pragma unroll
  for (int bt = 0; bt < 2; ++bt) {
    const int row = rb + wv * 32 + bt * 16 + fl;         // n = emb row
    u16* __restrict__ orow = xz + ((size_t)(dir * BATCH * TSEQ) + row) * G4;
#pragma unroll
    for (int i = 0; i < 8; ++i) {
      const int mb = cb1 + i * 16 + quad * 4;            // m = gate col (4 consecutive)
      const float4 bb = *(const float4*)&bias[mb];
      f32x4v v = acc[bt][i];
      uint2 pk;
      pk.x = packf16(v[0] + bb.x, v[1] + bb.y);
      pk.y = packf16(v[2] + bb.z, v[3] + bb.w);
      *(uint2*)&orow[mb] = pk;
    }
  }
}

// ---------------- K2: LSTM recurrence — one block per chain ----------------
// 128 blocks x 512 threads (8 waves = 2 waves/SIMD). waves_per_eu(2,2) pins the
// register budget at 256 VGPRs so the 192 weight u32 stay RESIDENT (round-3
// showed VGPR_Count=128 + 79MB excess WRITE_SIZE = spill-to-scratch).
__global__ void __launch_bounds__(512)
    __attribute__((amdgpu_waves_per_eu(2, 2))) lstm_k(
    const u16* __restrict__ xz, const float* __restrict__ Wr_f,
    const float* __restrict__ Wr_b, const int* __restrict__ lengths,
    u16* __restrict__ hcat)
{
  const int chain = blockIdx.x;
  const int dir   = chain >> 6;
  const int batch = chain & 63;
  const int tid = threadIdx.x;
  const float* __restrict__ Wr = dir ? Wr_b : Wr_f;

  __shared__ __align__(16) u32 wlds[16][512][4];  // 128 KB: c1 weights, k-pairs 64..127
  __shared__ __align__(16) u32 hp[128];           // packed h(t-1), f16x2
  __shared__ float zbuf[1024];

  const int c0 = tid, c1 = 512 + tid;
  u32 w0r[128];                          // c0 weights, k-pairs 0..127
  u32 w1r[64];                           // c1 weights, k-pairs 0..63
#pragma unroll
  for (int j = 0; j < 128; ++j)
    w0r[j] = packf16(Wr[(size_t)(2 * j) * G4 + c0],
                     Wr[(size_t)(2 * j + 1) * G4 + c0]);
#pragma unroll
  for (int j = 0; j < 64; ++j)
    w1r[j] = packf16(Wr[(size_t)(2 * j) * G4 + c1],
                     Wr[(size_t)(2 * j + 1) * G4 + c1]);
#pragma unroll
  for (int g = 0; g < 16; ++g)
#pragma unroll
    for (int u = 0; u < 4; ++u) {
      int kp = 64 + g * 4 + u;
      wlds[g][tid][u] = packf16(Wr[(size_t)(2 * kp) * G4 + c1],
                                Wr[(size_t)(2 * kp + 1) * G4 + c1]);
    }
  if (tid < 128) hp[tid] = 0u;

  float c = 0.f, h = 0.f;
  const int len = lengths[batch];
  const u16* __restrict__ xzb = xz + (size_t)(dir * BATCH + batch) * TSEQ * G4;
  u16* __restrict__ hrow = hcat + (size_t)batch * TSEQ * 512 + dir * 256;
  const int lane = tid & 63;
  __syncthreads();

  int tt = dir ? (TSEQ - 1) : 0;
  const int ttstep = dir ? -1 : 1;
  u16 x0 = xzb[(size_t)tt * G4 + c0];
  u16 x1 = xzb[(size_t)tt * G4 + c1];

  for (int st = 0; st < TSEQ; ++st) {
    const int ttn = (st == TSEQ - 1) ? tt : tt + ttstep;
    u16 x0n = xzb[(size_t)ttn * G4 + c0];  // prefetch next step's xz
    u16 x1n = xzb[(size_t)ttn * G4 + c1];

    // lane L holds hp[2L], hp[2L+1]; readlane broadcasts via SGPRs
    const uint2 hv2 = *(const uint2*)&hp[lane * 2];

    float a0 = (float)__builtin_bit_cast(f16, x0);
    float a1 = (float)__builtin_bit_cast(f16, x1);
#pragma unroll
    for (int j = 0; j < 32; ++j) {         // k-pairs 0..63: both cols from VGPR
      u32 s0 = (u32)__builtin_amdgcn_readlane((int)hv2.x, j);
      u32 s1 = (u32)__builtin_amdgcn_readlane((int)hv2.y, j);
      a0 = fdot2(w0r[2 * j], s0, a0);     a0 = fdot2(w0r[2 * j + 1], s1, a0);
      a1 = fdot2(w1r[2 * j], s0, a1);     a1 = fdot2(w1r[2 * j + 1], s1, a1);
    }
#pragma unroll
    for (int g = 0; g < 16; ++g) {         // k-pairs 64..127: c1 weights from LDS
      uint4 wl = *(const uint4*)&wlds[g][tid][0];
      const int j = 32 + 2 * g;
      u32 s0 = (u32)__builtin_amdgcn_readlane((int)hv2.x, j);
      u32 s1 = (u32)__builtin_amdgcn_readlane((int)hv2.y, j);
      a0 = fdot2(w0r[2 * j], s0, a0);     a0 = fdot2(w0r[2 * j + 1], s1, a0);
      a1 = fdot2(wl.x, s0, a1);           a1 = fdot2(wl.y, s1, a1);
      u32 s2 = (u32)__builtin_amdgcn_readlane((int)hv2.x, j + 1);
      u32 s3 = (u32)__builtin_amdgcn_readlane((int)hv2.y, j + 1);
      a0 = fdot2(w0r[2 * j + 2], s2, a0); a0 = fdot2(w0r[2 * j + 3], s3, a0);
      a1 = fdot2(wl.z, s2, a1);           a1 = fdot2(wl.w, s3, a1);
    }
    zbuf[c0] = a0;
    zbuf[c1] = a1;
    __syncthreads();

    if (tid < 256) {                       // waves 0-3: combine gates for k = tid
      float zi = zbuf[tid], zf = zbuf[256 + tid];
      float zg = zbuf[512 + tid], zo = zbuf[768 + tid];
      float ig = sigm_fast(zi);
      float fg = sigm_fast(zf);
      float gg = tanh_fast(zg);
      float og = sigm_fast(zo);
      float cn = fg * c + ig * gg;
      float hn = og * tanh_fast(cn);
      if (tt < len) { c = cn; h = hn; }    // masked step: hold state
      u32 hbits = packf16(h, h);
      hrow[(size_t)tt * 512 + tid] = (u16)(hbits & 0xffffu);  // f16 h for dense
      float ho = __shfl_xor(h, 1);
      if (!(tid & 1)) hp[tid >> 1] = packf16(h, ho);
    }
    __syncthreads();
    x0 = x0n; x1 = x1n; tt = ttn;
  }
}

// ---------------- K3: logits = hcat @ dense_W + dense_b ----------------
__global__ __launch_bounds__(256) void dense_k(
    const u16* __restrict__ hcat, const float* __restrict__ W,
    const float* __restrict__ bias, float* __restrict__ out)
{
  const int lane = threadIdx.x & 63;
  const int wv = threadIdx.x >> 6;
  const int rowbase = (blockIdx.x * 4 + wv) * 8;
  for (int rr = 0; rr < 8; ++rr) {
    const int row = rowbase + rr;
    const u16* __restrict__ hr = hcat + (size_t)row * 512;
    float hv[8];
#pragma unroll
    for (int i = 0; i < 8; ++i)
      hv[i] = (float)__builtin_bit_cast(f16, hr[i * 64 + lane]);
    float myout = 0.f;
#pragma unroll
    for (int cc = 0; cc < 9; ++cc) {
      float p = 0.f;
#pragma unroll
      for (int i = 0; i < 8; ++i)
        p = fmaf(hv[i], W[(size_t)(i * 64 + lane) * 9 + cc], p);
#pragma unroll
      for (int o = 32; o > 0; o >>= 1) p += __shfl_xor(p, o);
      if (lane == cc) myout = p + bias[cc];
    }
    if (lane < 9) out[(size_t)row * 9 + lane] = myout;
  }
}

// ---------------- K4: CRF log-likelihood + trans copy ----------------
__global__ __launch_bounds__(64) void crf_k(
    const float* __restrict__ logits, const int* __restrict__ tags,
    const int* __restrict__ lengths, const float* __restrict__ trans,
    float* __restrict__ out_ll, float* __restrict__ out_trans)
{
  const int b = blockIdx.x;
  const int lane = threadIdx.x;
  const int len = lengths[b];
  const float* __restrict__ lg = logits + (size_t)b * TSEQ * NCLS;
  const int* __restrict__ tg = tags + (size_t)b * TSEQ;

  float ua = 0.f, ba = 0.f;
  for (int t = lane; t < TSEQ; t += 64) {
    int tag = tg[t];
    if (t < len) ua += lg[t * 9 + tag];
    if (t < len - 1) ba += trans[tag * 9 + tg[t + 1]];
  }
  float s = ua + ba;
#pragma unroll
  for (int o = 32; o > 0; o >>= 1) s += __shfl_xor(s, o);

  const int j = (lane < 9) ? lane : 0;
  float trc[9], alpha[9];
#pragma unroll
  for (int i = 0; i < 9; ++i) trc[i] = trans[i * 9 + j];
#pragma unroll
  for (int i = 0; i < 9; ++i) alpha[i] = lg[i];
  for (int t = 1; t < TSEQ; ++t) {
    if (t >= len) break;                 // mask is monotone
    float m = -1e30f;
#pragma unroll
    for (int i = 0; i < 9; ++i) m = fmaxf(m, alpha[i] + trc[i]);
    float ss = 0.f;
#pragma unroll
    for (int i = 0; i < 9; ++i) ss += __expf(alpha[i] + trc[i] - m);
    float nj = __logf(ss) + m + lg[t * 9 + j];
#pragma unroll
    for (int i = 0; i < 9; ++i) alpha[i] = __shfl(nj, i);
  }
  float m2 = -1e30f;
#pragma unroll
  for (int i = 0; i < 9; ++i) m2 = fmaxf(m2, alpha[i]);
  float s2 = 0.f;
#pragma unroll
  for (int i = 0; i < 9; ++i) s2 += __expf(alpha[i] - m2);
  float lse = __logf(s2) + m2;
  if (lane == 0) out_ll[b] = s - lse;
  if (b == 0)
    for (int i = lane; i < 81; i += 64) out_trans[i] = trans[i];
}

// ---------------- launch ----------------
extern "C" void kernel_launch(void* const* d_in, const int* in_sizes, int n_in,
                              void* d_out, int out_size, void* d_ws, size_t ws_size,
                              hipStream_t stream)
{
  const int*   inputs  = (const int*)d_in[0];
  const int*   lengths = (const int*)d_in[1];
  const int*   targets = (const int*)d_in[2];
  const float* emb     = (const float*)d_in[3];
  const float* Wk_f    = (const float*)d_in[4];
  const float* Wr_f    = (const float*)d_in[5];
  const float* b_f     = (const float*)d_in[6];
  const float* Wk_b    = (const float*)d_in[7];
  const float* Wr_b    = (const float*)d_in[8];
  const float* b_b     = (const float*)d_in[9];
  const float* dense_W = (const float*)d_in[10];
  const float* dense_b = (const float*)d_in[11];
  const float* trans   = (const float*)d_in[12];

  char* ws = (char*)d_ws;
  u16* wkt    = (u16*)ws;                                    //  1,310,720 B
  u16* embf16 = (u16*)(ws + 1310720ull);                     // 19,200,000 B
  u16* xz     = (u16*)(ws + 1310720ull + 19200000ull);       // 134,217,728 B
  u16* hcat   = (u16*)(ws + 1310720ull + 19200000ull + 134217728ull); // 33,554,432 B

  float* out_logits = (float*)d_out;
  float* out_ll     = out_logits + (size_t)BATCH * TSEQ * NCLS;
  float* out_trans  = out_ll + BATCH;

  hipLaunchKernelGGL(embcvt_k, dim3(1875), dim3(256), 0, stream, emb, embf16);
  hipLaunchKernelGGL(wkt_k, dim3(64, 2), dim3(256), 0, stream, Wk_f, Wk_b, wkt);
  hipLaunchKernelGGL(xz_gemm_k, dim3(16, 256), dim3(256), 0, stream,
                     inputs, wkt, embf16, b_f, b_b, xz);
  hipLaunchKernelGGL(lstm_k, dim3(128), dim3(512), 0, stream,
                     xz, Wr_f, Wr_b, lengths, hcat);
  hipLaunchKernelGGL(dense_k, dim3(1024), dim3(256), 0, stream,
                     hcat, dense_W, dense_b, out_logits);
  hipLaunchKernelGGL(crf_k, dim3(64), dim3(64), 0, stream,
                     out_logits, targets, lengths, trans, out_ll, out_trans);
}

// Round 5
// 1391.210 us; speedup vs baseline: 2.5350x; 1.0150x over previous
//
#include <hip/hip_runtime.h>
#include <cstdint>
#include <cstddef>

typedef unsigned int  u32;
typedef unsigned short u16;
typedef _Float16 f16;
typedef _Float16 f16x2 __attribute__((ext_vector_type(2)));
typedef _Float16 half8 __attribute__((ext_vector_type(8)));
typedef float    f32x4v __attribute__((ext_vector_type(4)));
typedef u32      u32x16 __attribute__((ext_vector_type(16)));

#define BATCH 64
#define TSEQ  512
#define DEMB  300
#define KPAD  320
#define HDIM  256
#define G4    1024
#define NCLS  9

__device__ __forceinline__ float fdot2(u32 a, u32 b, float c) {
  return __builtin_amdgcn_fdot2(__builtin_bit_cast(f16x2, a),
                                __builtin_bit_cast(f16x2, b), c, false);
}
__device__ __forceinline__ u32 packf16(float a, float b) {
  f16x2 v; v.x = (f16)a; v.y = (f16)b;
  return __builtin_bit_cast(u32, v);
}
__device__ __forceinline__ float sigm_fast(float x) {
  return __builtin_amdgcn_rcpf(1.f + __expf(-x));
}
__device__ __forceinline__ float tanh_fast(float x) {
  float ax = __builtin_fabsf(x);
  float e = __expf(-2.f * ax);
  float t = (1.f - e) * __builtin_amdgcn_rcpf(1.f + e);
  return copysignf(t, x);
}

// ---------------- P1: embf16[v][320] = f16(emb[v][0..299]), zero-pad 300..319 ----
__global__ __launch_bounds__(256) void embcvt_k(const float* __restrict__ emb,
                                                u16* __restrict__ out) {
  const int v  = blockIdx.x * 16 + (threadIdx.x >> 4);
  const int kc = threadIdx.x & 15;
  u32* __restrict__ dst = (u32*)(out + (size_t)v * KPAD + kc * 20);
  if (kc < 15) {
    const float* __restrict__ src = emb + (size_t)v * DEMB + kc * 20;
    float tmp[20];
#pragma unroll
    for (int j = 0; j < 20; ++j) tmp[j] = src[j];
#pragma unroll
    for (int j = 0; j < 10; ++j) dst[j] = packf16(tmp[2 * j], tmp[2 * j + 1]);
  } else {
#pragma unroll
    for (int j = 0; j < 10; ++j) dst[j] = 0u;
  }
}

// ---------------- P2: wkt[dir][col][320] = f16(Wk[k][col]), zero-pad k>=300 -----
__global__ __launch_bounds__(256) void wkt_k(const float* __restrict__ Wk_f,
                                             const float* __restrict__ Wk_b,
                                             u16* __restrict__ wkt) {
  const int dir = blockIdx.y;
  const float* __restrict__ Wk = dir ? Wk_b : Wk_f;
  const int col = blockIdx.x * 16 + (threadIdx.x >> 4);
  const int kc  = threadIdx.x & 15;
  u32* __restrict__ dst = (u32*)(wkt + ((size_t)dir * G4 + col) * KPAD + kc * 20);
  if (kc < 15) {
    float tmp[20];
#pragma unroll
    for (int j = 0; j < 20; ++j) tmp[j] = Wk[(size_t)(kc * 20 + j) * G4 + col];
#pragma unroll
    for (int j = 0; j < 10; ++j) dst[j] = packf16(tmp[2 * j], tmp[2 * j + 1]);
  } else {
#pragma unroll
    for (int j = 0; j < 10; ++j) dst[j] = 0u;
  }
}

// ---------------- K1: xz = emb[inputs] @ Wk + b  (MFMA f16) ----------------
__global__ __launch_bounds__(256) void xz_gemm_k(
    const int* __restrict__ inputs, const u16* __restrict__ wkt,
    const u16* __restrict__ embf16, const float* __restrict__ b_f,
    const float* __restrict__ b_b, u16* __restrict__ xz)
{
  __shared__ __align__(16) u16 As[128 * 40];   // [m][k], k-major, pad 32->40
  __shared__ __align__(16) u16 Bs[128 * 40];   // [n][k], k-major
  const int tid  = threadIdx.x;
  const int wv   = tid >> 6, lane = tid & 63;
  const int quad = lane >> 4, fl = lane & 15;
  const int cbi  = blockIdx.x;                 // 0..15
  const int dir  = cbi >> 3;
  const int cb1  = (cbi & 7) * 128;
  const int rb   = blockIdx.y * 128;
  const float* __restrict__ bias = dir ? b_b : b_f;

  const int sm = tid >> 1, sh = (tid & 1) * 16;          // staging row, k-half
  const int vrow = inputs[rb + sm];
  const u16* __restrict__ asrc = wkt + ((size_t)(dir * G4) + cb1 + sm) * KPAD + sh;
  const u16* __restrict__ bsrc = embf16 + (size_t)vrow * KPAD + sh;

  f32x4v acc[2][8];
#pragma unroll
  for (int bt = 0; bt < 2; ++bt)
#pragma unroll
    for (int i = 0; i < 8; ++i) acc[bt][i] = (f32x4v){0.f, 0.f, 0.f, 0.f};

  for (int kt = 0; kt < 10; ++kt) {
    const int k0 = kt * 32;
    uint4 a0v = *(const uint4*)(asrc + k0);
    uint4 a1v = *(const uint4*)(asrc + k0 + 8);
    uint4 b0v = *(const uint4*)(bsrc + k0);
    uint4 b1v = *(const uint4*)(bsrc + k0 + 8);
    *(uint4*)&As[sm * 40 + sh]     = a0v;
    *(uint4*)&As[sm * 40 + sh + 8] = a1v;
    *(uint4*)&Bs[sm * 40 + sh]     = b0v;
    *(uint4*)&Bs[sm * 40 + sh + 8] = b1v;
    __syncthreads();
    half8 bf[2];
#pragma unroll
    for (int bt = 0; bt < 2; ++bt)
      bf[bt] = *(const half8*)&Bs[(wv * 32 + bt * 16 + fl) * 40 + quad * 8];
#pragma unroll
    for (int i = 0; i < 8; ++i) {
      half8 af = *(const half8*)&As[(i * 16 + fl) * 40 + quad * 8];
      acc[0][i] = __builtin_amdgcn_mfma_f32_16x16x32_f16(af, bf[0], acc[0][i], 0, 0, 0);
      acc[1][i] = __builtin_amdgcn_mfma_f32_16x16x32_f16(af, bf[1], acc[1][i], 0, 0, 0);
    }
    __syncthreads();
  }
#pragma unroll
  for (int bt = 0; bt < 2; ++bt) {
    const int row = rb + wv * 32 + bt * 16 + fl;         // n = emb row
    u16* __restrict__ orow = xz + ((size_t)(dir * BATCH * TSEQ) + row) * G4;
#pragma unroll
    for (int i = 0; i < 8; ++i) {
      const int mb = cb1 + i * 16 + quad * 4;            // m = gate col (4 consecutive)
      const float4 bb = *(const float4*)&bias[mb];
      f32x4v v = acc[bt][i];
      uint2 pk;
      pk.x = packf16(v[0] + bb.x, v[1] + bb.y);
      pk.y = packf16(v[2] + bb.z, v[3] + bb.w);
      *(uint2*)&orow[mb] = pk;
    }
  }
}

// ---------------- K2: LSTM recurrence — one block per chain ----------------
// 128 blocks x 512 threads (8 waves = 2 waves/SIMD -> 256-VGPR budget via
// __launch_bounds__(512,2)). Weights held in NAMED ext_vector_type(16) SSA
// values (no alloca) — rounds 3/4 showed scalar C arrays stayed in scratch
// (VGPR_Count=128, +84MB WRITE_SIZE, L2/L3-BW-bound reloads).
#define G16(V0, V1, m)                                                   \
  _Pragma("unroll")                                                      \
  for (int t = 0; t < 8; ++t) {                                          \
    u32 s0 = (u32)__builtin_amdgcn_readlane((int)hv2.x, 8 * (m) + t);    \
    u32 s1 = (u32)__builtin_amdgcn_readlane((int)hv2.y, 8 * (m) + t);    \
    a0 = fdot2(V0[2 * t], s0, a0);  a0 = fdot2(V0[2 * t + 1], s1, a0);   \
    a1 = fdot2(V1[2 * t], s0, a1);  a1 = fdot2(V1[2 * t + 1], s1, a1);   \
  }

#define G16L(V0, m)                                                      \
  _Pragma("unroll")                                                      \
  for (int i = 0; i < 4; ++i) {                                          \
    uint4 wl = *(const uint4*)&wlds[4 * ((m) - 4) + i][tid][0];          \
    u32 s0 = (u32)__builtin_amdgcn_readlane((int)hv2.x, 8 * (m) + 2 * i);\
    u32 s1 = (u32)__builtin_amdgcn_readlane((int)hv2.y, 8 * (m) + 2 * i);\
    u32 s2 = (u32)__builtin_amdgcn_readlane((int)hv2.x, 8 * (m) + 2 * i + 1);\
    u32 s3 = (u32)__builtin_amdgcn_readlane((int)hv2.y, 8 * (m) + 2 * i + 1);\
    a0 = fdot2(V0[4 * i], s0, a0);      a1 = fdot2(wl.x, s0, a1);        \
    a0 = fdot2(V0[4 * i + 1], s1, a0);  a1 = fdot2(wl.y, s1, a1);        \
    a0 = fdot2(V0[4 * i + 2], s2, a0);  a1 = fdot2(wl.z, s2, a1);        \
    a0 = fdot2(V0[4 * i + 3], s3, a0);  a1 = fdot2(wl.w, s3, a1);        \
  }

__device__ __forceinline__ u32x16 load_wcol(const float* __restrict__ Wr,
                                            int col, int base) {
  u32x16 v;
#pragma unroll
  for (int j = 0; j < 16; ++j)
    v[j] = packf16(Wr[(size_t)(2 * (base + j)) * G4 + col],
                   Wr[(size_t)(2 * (base + j) + 1) * G4 + col]);
  return v;
}

__global__ __launch_bounds__(512, 2) void lstm_k(
    const u16* __restrict__ xz, const float* __restrict__ Wr_f,
    const float* __restrict__ Wr_b, const int* __restrict__ lengths,
    u16* __restrict__ hcat)
{
  const int chain = blockIdx.x;
  const int dir   = chain >> 6;
  const int batch = chain & 63;
  const int tid = threadIdx.x;
  const float* __restrict__ Wr = dir ? Wr_b : Wr_f;

  __shared__ __align__(16) u32 wlds[16][512][4];  // 128 KB: c1 weights, k-pairs 64..127
  __shared__ __align__(16) u32 hp[128];           // packed h(t-1), f16x2
  __shared__ float zbuf[1024];

  const int c0 = tid, c1 = 512 + tid;
  // c0 weights, k-pairs 0..127 (8 x 16 = 128 regs), SSA vectors
  u32x16 w0_0 = load_wcol(Wr, c0, 0),   w0_1 = load_wcol(Wr, c0, 16);
  u32x16 w0_2 = load_wcol(Wr, c0, 32),  w0_3 = load_wcol(Wr, c0, 48);
  u32x16 w0_4 = load_wcol(Wr, c0, 64),  w0_5 = load_wcol(Wr, c0, 80);
  u32x16 w0_6 = load_wcol(Wr, c0, 96),  w0_7 = load_wcol(Wr, c0, 112);
  // c1 weights, k-pairs 0..63 (4 x 16 = 64 regs)
  u32x16 w1_0 = load_wcol(Wr, c1, 0),   w1_1 = load_wcol(Wr, c1, 16);
  u32x16 w1_2 = load_wcol(Wr, c1, 32),  w1_3 = load_wcol(Wr, c1, 48);
#pragma unroll
  for (int g = 0; g < 16; ++g)
#pragma unroll
    for (int u = 0; u < 4; ++u) {
      int kp = 64 + g * 4 + u;
      wlds[g][tid][u] = packf16(Wr[(size_t)(2 * kp) * G4 + c1],
                                Wr[(size_t)(2 * kp + 1) * G4 + c1]);
    }
  if (tid < 128) hp[tid] = 0u;

  float c = 0.f, h = 0.f;
  const int len = lengths[batch];
  const u16* __restrict__ xzb = xz + (size_t)(dir * BATCH + batch) * TSEQ * G4;
  u16* __restrict__ hrow = hcat + (size_t)batch * TSEQ * 512 + dir * 256;
  const int lane = tid & 63;
  __syncthreads();

  int tt = dir ? (TSEQ - 1) : 0;
  const int ttstep = dir ? -1 : 1;
  u16 x0 = xzb[(size_t)tt * G4 + c0];
  u16 x1 = xzb[(size_t)tt * G4 + c1];

  for (int st = 0; st < TSEQ; ++st) {
    const int ttn = (st == TSEQ - 1) ? tt : tt + ttstep;
    u16 x0n = xzb[(size_t)ttn * G4 + c0];  // prefetch next step's xz
    u16 x1n = xzb[(size_t)ttn * G4 + c1];

    // lane L holds hp[2L], hp[2L+1] => k-pairs 2L (x) and 2L+1 (y)
    const uint2 hv2 = *(const uint2*)&hp[lane * 2];

    float a0 = (float)__builtin_bit_cast(f16, x0);
    float a1 = (float)__builtin_bit_cast(f16, x1);
    G16(w0_0, w1_0, 0)  G16(w0_1, w1_1, 1)
    G16(w0_2, w1_2, 2)  G16(w0_3, w1_3, 3)
    G16L(w0_4, 4)  G16L(w0_5, 5)  G16L(w0_6, 6)  G16L(w0_7, 7)
    zbuf[c0] = a0;
    zbuf[c1] = a1;
    __syncthreads();

    if (tid < 256) {                       // waves 0-3: combine gates for k = tid
      float zi = zbuf[tid], zf = zbuf[256 + tid];
      float zg = zbuf[512 + tid], zo = zbuf[768 + tid];
      float ig = sigm_fast(zi);
      float fg = sigm_fast(zf);
      float gg = tanh_fast(zg);
      float og = sigm_fast(zo);
      float cn = fg * c + ig * gg;
      float hn = og * tanh_fast(cn);
      if (tt < len) { c = cn; h = hn; }    // masked step: hold state
      u32 hbits = packf16(h, h);
      hrow[(size_t)tt * 512 + tid] = (u16)(hbits & 0xffffu);  // f16 h for dense
      float ho = __shfl_xor(h, 1);
      if (!(tid & 1)) hp[tid >> 1] = packf16(h, ho);
    }
    __syncthreads();
    x0 = x0n; x1 = x1n; tt = ttn;
  }
}

// ---------------- K3: logits = hcat @ dense_W + dense_b ----------------
__global__ __launch_bounds__(256) void dense_k(
    const u16* __restrict__ hcat, const float* __restrict__ W,
    const float* __restrict__ bias, float* __restrict__ out)
{
  const int lane = threadIdx.x & 63;
  const int wv = threadIdx.x >> 6;
  const int rowbase = (blockIdx.x * 4 + wv) * 8;
  for (int rr = 0; rr < 8; ++rr) {
    const int row = rowbase + rr;
    const u16* __restrict__ hr = hcat + (size_t)row * 512;
    float hv[8];
#pragma unroll
    for (int i = 0; i < 8; ++i)
      hv[i] = (float)__builtin_bit_cast(f16, hr[i * 64 + lane]);
    float myout = 0.f;
#pragma unroll
    for (int cc = 0; cc < 9; ++cc) {
      float p = 0.f;
#pragma unroll
      for (int i = 0; i < 8; ++i)
        p = fmaf(hv[i], W[(size_t)(i * 64 + lane) * 9 + cc], p);
#pragma unroll
      for (int o = 32; o > 0; o >>= 1) p += __shfl_xor(p, o);
      if (lane == cc) myout = p + bias[cc];
    }
    if (lane < 9) out[(size_t)row * 9 + lane] = myout;
  }
}

// ---------------- K4: CRF log-likelihood + trans copy ----------------
__global__ __launch_bounds__(64) void crf_k(
    const float* __restrict__ logits, const int* __restrict__ tags,
    const int* __restrict__ lengths, const float* __restrict__ trans,
    float* __restrict__ out_ll, float* __restrict__ out_trans)
{
  const int b = blockIdx.x;
  const int lane = threadIdx.x;
  const int len = lengths[b];
  const float* __restrict__ lg = logits + (size_t)b * TSEQ * NCLS;
  const int* __restrict__ tg = tags + (size_t)b * TSEQ;

  float ua = 0.f, ba = 0.f;
  for (int t = lane; t < TSEQ; t += 64) {
    int tag = tg[t];
    if (t < len) ua += lg[t * 9 + tag];
    if (t < len - 1) ba += trans[tag * 9 + tg[t + 1]];
  }
  float s = ua + ba;
#pragma unroll
  for (int o = 32; o > 0; o >>= 1) s += __shfl_xor(s, o);

  const int j = (lane < 9) ? lane : 0;
  float trc[9], alpha[9];
#pragma unroll
  for (int i = 0; i < 9; ++i) trc[i] = trans[i * 9 + j];
#pragma unroll
  for (int i = 0; i < 9; ++i) alpha[i] = lg[i];
  for (int t = 1; t < TSEQ; ++t) {
    if (t >= len) break;                 // mask is monotone
    float m = -1e30f;
#pragma unroll
    for (int i = 0; i < 9; ++i) m = fmaxf(m, alpha[i] + trc[i]);
    float ss = 0.f;
#pragma unroll
    for (int i = 0; i < 9; ++i) ss += __expf(alpha[i] + trc[i] - m);
    float nj = __logf(ss) + m + lg[t * 9 + j];
#pragma unroll
    for (int i = 0; i < 9; ++i) alpha[i] = __shfl(nj, i);
  }
  float m2 = -1e30f;
#pragma unroll
  for (int i = 0; i < 9; ++i) m2 = fmaxf(m2, alpha[i]);
  float s2 = 0.f;
#pragma unroll
  for (int i = 0; i < 9; ++i) s2 += __expf(alpha[i] - m2);
  float lse = __logf(s2) + m2;
  if (lane == 0) out_ll[b] = s - lse;
  if (b == 0)
    for (int i = lane; i < 81; i += 64) out_trans[i] = trans[i];
}

// ---------------- launch ----------------
extern "C" void kernel_launch(void* const* d_in, const int* in_sizes, int n_in,
                              void* d_out, int out_size, void* d_ws, size_t ws_size,
                              hipStream_t stream)
{
  const int*   inputs  = (const int*)d_in[0];
  const int*   lengths = (const int*)d_in[1];
  const int*   targets = (const int*)d_in[2];
  const float* emb     = (const float*)d_in[3];
  const float* Wk_f    = (const float*)d_in[4];
  const float* Wr_f    = (const float*)d_in[5];
  const float* b_f     = (const float*)d_in[6];
  const float* Wk_b    = (const float*)d_in[7];
  const float* Wr_b    = (const float*)d_in[8];
  const float* b_b     = (const float*)d_in[9];
  const float* dense_W = (const float*)d_in[10];
  const float* dense_b = (const float*)d_in[11];
  const float* trans   = (const float*)d_in[12];

  char* ws = (char*)d_ws;
  u16* wkt    = (u16*)ws;                                    //  1,310,720 B
  u16* embf16 = (u16*)(ws + 1310720ull);                     // 19,200,000 B
  u16* xz     = (u16*)(ws + 1310720ull + 19200000ull);       // 134,217,728 B
  u16* hcat   = (u16*)(ws + 1310720ull + 19200000ull + 134217728ull); // 33,554,432 B

  float* out_logits = (float*)d_out;
  float* out_ll     = out_logits + (size_t)BATCH * TSEQ * NCLS;
  float* out_trans  = out_ll + BATCH;

  hipLaunchKernelGGL(embcvt_k, dim3(1875), dim3(256), 0, stream, emb, embf16);
  hipLaunchKernelGGL(wkt_k, dim3(64, 2), dim3(256), 0, stream, Wk_f, Wk_b, wkt);
  hipLaunchKernelGGL(xz_gemm_k, dim3(16, 256), dim3(256), 0, stream,
                     inputs, wkt, embf16, b_f, b_b, xz);
  hipLaunchKernelGGL(lstm_k, dim3(128), dim3(512), 0, stream,
                     xz, Wr_f, Wr_b, lengths, hcat);
  hipLaunchKernelGGL(dense_k, dim3(1024), dim3(256), 0, stream,
                     hcat, dense_W, dense_b, out_logits);
  hipLaunchKernelGGL(crf_k, dim3(64), dim3(64), 0, stream,
                     out_logits, targets, lengths, trans, out_ll, out_trans);
}